// Round 7
// baseline (32.747 us; speedup 1.0000x reference)
//
#include <hip/hip_runtime.h>

#define NEG_SLOPE 0.01f

typedef _Float16 f16;
typedef _Float16 f16x4 __attribute__((ext_vector_type(4)));
typedef float    f32x4 __attribute__((ext_vector_type(4)));

__device__ __forceinline__ float leaky(float v) {
    // 0 < slope < 1  =>  leaky(v) == max(v, slope*v)
    return fmaxf(v, NEG_SLOPE * v);
}

// ws layout (float indices):
//   [0,      8192)    node_out f32            (B*N)
//   [8192,   73728)   pjh  f16[8192][16]      x@Wc1_j
//   [73728,  139264)  piuh f16[8192][16]      x@Wc1_i + bc1
//   [139264, 401408)  S    f32[512][512]      sigmoid(A_param), diag=0
//   [401408, 401664)  wlh  f16[64][8]         per-lane {w2lo[4], w2hi[4]}
//   [401664, 401920)  c1s  f32[64][4]         per-lane bc2 fragment
//   [401920, 402176)  w3s  f32[64][4]         per-lane Wc3 fragment
#define WS_PJH  8192
#define WS_PIUH 73728
#define WS_S    139264
#define WS_WLH  401408
#define WS_C1   401664
#define WS_W3   401920

// ---------------- Kernel 1: node MLP + precompute ----------------
__global__ __launch_bounds__(256) void k1_fused(
    const float* __restrict__ x,
    const float* __restrict__ Wn1, const float* __restrict__ bn1,
    const float* __restrict__ Wn2, const float* __restrict__ bn2,
    const float* __restrict__ Wn3, const float* __restrict__ bn3,
    const float* __restrict__ Wc1, const float* __restrict__ bc1,
    const float* __restrict__ Wc2, const float* __restrict__ bc2,
    const float* __restrict__ Wc3,
    const float* __restrict__ A_param,
    float* __restrict__ ws, float* __restrict__ out)
{
    __shared__ float sh[4][64];
    const int t    = threadIdx.x;
    const int lane = t & 63;
    const int wv   = t >> 6;
    const int row  = blockIdx.x * 4 + wv;   // b*N + n

    const float x0 = x[row * 2 + 0];
    const float x1 = x[row * 2 + 1];

    // node layer 1
    const float h = leaky(fmaf(x0, Wn1[lane], fmaf(x1, Wn1[64 + lane], bn1[lane])));
    sh[wv][lane] = h;
    __syncthreads();

    // fused: sigmoid(A_param) table, diag zeroed (blocks 0..1023 cover 512*512)
    {
        const int g = blockIdx.x * 256 + t;
        if (g < 512 * 512) {
            const int i = g >> 9, j = g & 511;
            const float a = A_param[g];
            float s = __fdividef(1.0f, 1.0f + __expf(-a));
            if (i == j) s = 0.0f;
            ws[WS_S + g] = s;
        }
    }

    // fused: per-lane packed weight fragments for k2 (block 0 only)
    if (blockIdx.x == 0 && t < 64) {
        const int p  = t & 15;
        const int c4 = (t >> 4) << 2;
        f16   wl[8];
        f32x4 c1v, w3v;
        #pragma unroll
        for (int e = 0; e < 4; ++e) {
            const int c = c4 + e;
            const float w2 = Wc2[c * 16 + p];
            const f16 hw = (f16)w2;
            wl[4 + e] = hw;
            wl[e]     = (f16)(w2 - (float)hw);
            c1v[e] = bc2[c];
            w3v[e] = Wc3[c];
        }
        f16* wlh = (f16*)(ws + WS_WLH);
        #pragma unroll
        for (int e = 0; e < 8; ++e) wlh[t * 8 + e] = wl[e];
        *reinterpret_cast<f32x4*>(ws + WS_C1 + t * 4) = c1v;
        *reinterpret_cast<f32x4*>(ws + WS_W3 + t * 4) = w3v;
    }

    // fused: pj / piu rows (f16) for the coupling MLP
    if (lane < 16) {
        f16* pjh  = (f16*)(ws + WS_PJH);
        f16* piuh = (f16*)(ws + WS_PIUH);
        const float pj = fmaf(x0, Wc1[lane], x1 * Wc1[16 + lane]);
        const float pi = fmaf(x0, Wc1[32 + lane], fmaf(x1, Wc1[48 + lane], bc1[lane]));
        pjh [row * 16 + lane] = (f16)pj;
        piuh[row * 16 + lane] = (f16)pi;
    }

    // node layer 2
    float acc = bn2[lane];
    #pragma unroll
    for (int c = 0; c < 64; ++c)
        acc = fmaf(sh[wv][c], Wn2[c * 64 + lane], acc);
    const float h2 = leaky(acc);

    // node layer 3 (64 -> 1)
    float p = h2 * Wn3[lane];
    #pragma unroll
    for (int off = 32; off > 0; off >>= 1)
        p += __shfl_xor(p, off, 64);
    if (lane == 0) {
        ws[row] = p + bn3[0];      // node_out
        out[row * 2 + 0] = x1;     // out0 = x[...,1]
    }
}

// ---------------- Kernel 2: pairwise coupling via MFMA ----------------
// 256-thread block = 4 independent waves; wave wv owns i = blockIdx.x*4+wv
// and all 32 j-tiles. No LDS, no barriers. Lane (p=l&15, c4=(l>>4)*4):
//   b1 = pk_max(s, 0.01*s), s = pjh4[j] + piuh4[i]     (packed f16)
//   d1 = Wc2^T(hi) x b1 + (Wc2^T(lo) x b1 + bc2)       (2 MFMAs, exact weights)
//   accE[e] += S[i,j]*leaky(d1[e]);  vS += S[i,j]
// pp = accE.w3 + 0.25*b3*vS; butterfly(64); lane 0 writes out1.
__global__ __launch_bounds__(256) void k2_pair_mfma(
    const float* __restrict__ bc3,
    const float* __restrict__ ws, float* __restrict__ out)
{
    const int t  = threadIdx.x;
    const int l  = t & 63;            // lane in wave
    const int wv = t >> 6;            // wave 0..3
    const int p  = l & 15;            // pair slot within tile
    const int c4 = (l >> 4) << 2;     // channel base (unused directly; baked into packs)
    (void)c4;
    const int bi = blockIdx.x * 4 + wv;   // b*512 + i
    const int b  = bi >> 9;
    const int i  = bi & 511;

    const float* node_out = ws;
    const f16*   pjh  = (const f16*)(ws + WS_PJH);
    const f16*   piuh = (const f16*)(ws + WS_PIUH);
    const float* S    = ws + WS_S;

    // prepacked per-lane fragments (3 aligned 16B loads)
    const f16* wlh = (const f16*)(ws + WS_WLH) + l * 8;
    const f16x4 w2lo = *reinterpret_cast<const f16x4*>(wlh);
    const f16x4 w2hi = *reinterpret_cast<const f16x4*>(wlh + 4);
    const f32x4 c1   = *reinterpret_cast<const f32x4*>(ws + WS_C1 + l * 4);
    const f32x4 w3v  = *reinterpret_cast<const f32x4*>(ws + WS_W3 + l * 4);
    const float b3   = bc3[0];

    const f16x4 piu4 = *reinterpret_cast<const f16x4*>(piuh + bi * 16 + (l >> 4) * 4);
    const f16x4 slope4 = {(f16)NEG_SLOPE, (f16)NEG_SLOPE, (f16)NEG_SLOPE, (f16)NEG_SLOPE};
    const f16*   pjb = pjh + b * 512 * 16 + (l >> 4) * 4;
    const float* Sr  = S + i * 512;

    float accE[4] = {0.0f, 0.0f, 0.0f, 0.0f};
    float vS = 0.0f;
    #pragma unroll 8
    for (int tt = 0; tt < 32; ++tt) {
        const int j = tt * 16 + p;
        const f16x4 pj4 = *reinterpret_cast<const f16x4*>(pjb + j * 16);

        const f16x4 s4 = pj4 + piu4;                                 // v_pk_add_f16
        const f16x4 b1 = __builtin_elementwise_max(s4, s4 * slope4); // pk_mul+pk_max

        f32x4 d1 = __builtin_amdgcn_mfma_f32_16x16x16f16(w2lo, b1, c1, 0, 0, 0);
        d1 = __builtin_amdgcn_mfma_f32_16x16x16f16(w2hi, b1, d1, 0, 0, 0);

        const float Sj = Sr[j];
        vS += Sj;
        #pragma unroll
        for (int e = 0; e < 4; ++e)
            accE[e] = fmaf(fmaxf(d1[e], NEG_SLOPE * d1[e]), Sj, accE[e]);
    }

    float pp = fmaf(accE[0], w3v[0],
               fmaf(accE[1], w3v[1],
               fmaf(accE[2], w3v[2], accE[3] * w3v[3])));
    pp = fmaf(0.25f * b3, vS, pp);     // 4-way lane duplication of S -> x0.25

    // sum over 16 pairs x 4 channel groups within the wave
    #pragma unroll
    for (int off = 32; off > 0; off >>= 1)
        pp += __shfl_xor(pp, off, 64);

    if (l == 0)
        out[bi * 2 + 1] = node_out[bi] + pp;
}

extern "C" void kernel_launch(void* const* d_in, const int* in_sizes, int n_in,
                              void* d_out, int out_size, void* d_ws, size_t ws_size,
                              hipStream_t stream) {
    const float* x       = (const float*)d_in[0];
    const float* Wn1     = (const float*)d_in[1];
    const float* bn1     = (const float*)d_in[2];
    const float* Wn2     = (const float*)d_in[3];
    const float* bn2     = (const float*)d_in[4];
    const float* Wn3     = (const float*)d_in[5];
    const float* bn3     = (const float*)d_in[6];
    const float* Wc1     = (const float*)d_in[7];
    const float* bc1     = (const float*)d_in[8];
    const float* Wc2     = (const float*)d_in[9];
    const float* bc2     = (const float*)d_in[10];
    const float* Wc3     = (const float*)d_in[11];
    const float* bc3     = (const float*)d_in[12];
    const float* A_param = (const float*)d_in[13];
    float* out = (float*)d_out;
    float* ws  = (float*)d_ws;

    const int BN = 16 * 512;          // 8192 rows

    k1_fused<<<BN / 4, 256, 0, stream>>>(x, Wn1, bn1, Wn2, bn2, Wn3, bn3,
                                         Wc1, bc1, Wc2, bc2, Wc3, A_param, ws, out);
    k2_pair_mfma<<<BN / 4, 256, 0, stream>>>(bc3, ws, out);
}